// Round 4
// baseline (315.163 us; speedup 1.0000x reference)
//
#include <hip/hip_runtime.h>
#include <hip/hip_bf16.h>

// Problem constants
#define DIMK   512
#define HEADS  8
#define DHEAD  64
#define SEQ    2048
#define BATCH  8
#define MROWS  (BATCH*SEQ)      // 16384
#define SCALE_LOG2E (0.044194173824159216f * 1.44269504088896340736f) // 512^-0.5 * log2(e)

typedef float fx4   __attribute__((ext_vector_type(4)));
typedef short bf16x8 __attribute__((ext_vector_type(8)));
typedef short bf16x4 __attribute__((ext_vector_type(4)));

__device__ __forceinline__ short f2bf(float f) {
    union { float f; unsigned u; } x; x.f = f;
    unsigned r = (x.u + 0x7FFFu + ((x.u >> 16) & 1u)) >> 16;   // RNE
    return (short)r;
}

// pack two floats to two bf16 (round-half-up) in one dword via v_perm_b32
__device__ __forceinline__ unsigned pk2bf(float a, float b) {
    union { float f; unsigned u; } A, B; A.f = a; B.f = b;
    return __builtin_amdgcn_perm(B.u + 0x8000u, A.u + 0x8000u, 0x07060302u);
}

// async global->LDS, 16B per lane; LDS dest = wave-uniform base + lane*16
__device__ __forceinline__ void ld16(const short* g, short* l) {
    __builtin_amdgcn_global_load_lds(
        (const __attribute__((address_space(1))) unsigned int*)g,
        (__attribute__((address_space(3))) unsigned int*)l, 16, 0, 0);
}

// ---------------------------------------------------------------- convert
__global__ __launch_bounds__(256) void cvt_kernel(const float* __restrict__ src,
                                                  short* __restrict__ dst) {
    int i = blockIdx.x * 256 + threadIdx.x;
    float4 v = ((const float4*)src)[i];
    bf16x4 o; o.x = f2bf(v.x); o.y = f2bf(v.y); o.z = f2bf(v.z); o.w = f2bf(v.w);
    ((bf16x4*)dst)[i] = o;
}

// ------------------------------------------------- weight transpose W[k][n] -> WT[n][k] bf16
__global__ __launch_bounds__(256) void wtrans_kernel(const float* __restrict__ Wq,
                                                     const float* __restrict__ Wk,
                                                     const float* __restrict__ Wv,
                                                     const float* __restrict__ Wo,
                                                     short* __restrict__ wT) {
    __shared__ float tile[32][33];
    const float* W = (blockIdx.z == 0) ? Wq : (blockIdx.z == 1) ? Wk
                   : (blockIdx.z == 2) ? Wv : Wo;
    short* dst = wT + (size_t)blockIdx.z * DIMK * DIMK;
    int n0 = blockIdx.x * 32, k0 = blockIdx.y * 32;
    int tx = threadIdx.x, ty = threadIdx.y;          // (32,8)
#pragma unroll
    for (int i = 0; i < 32; i += 8)
        tile[ty + i][tx] = W[(size_t)(k0 + ty + i) * DIMK + n0 + tx];
    __syncthreads();
#pragma unroll
    for (int i = 0; i < 32; i += 8)
        dst[(size_t)(n0 + ty + i) * DIMK + k0 + tx] = f2bf(tile[tx][ty + i]);
}

// ---------------------------------------------------------------- GEMM mainloop (m97-style)
// C(128x64) = A(128x512) @ BT(64x512)^T. Fragment-linear LDS, global_load_lds staging,
// double-buffered (24KB/buffer), BK=64, one barrier per K-iter.
// lds must be 2*12288 shorts. A,B row stride = 512 shorts.
__device__ __forceinline__ void gemm_ml2(const short* __restrict__ A,
                                         const short* __restrict__ B,
                                         short* lds, fx4 acc[2][4],
                                         int w, int lane, int q, int l15) {
    auto issue = [&](int k0, short* bb) {
#pragma unroll
        for (int j = 0; j < 4; j++) {           // A chunks: 16 total, 4 per wave
            int c = w * 4 + j, mt_g = c >> 1, ks = c & 1;
            ld16(A + (size_t)(mt_g * 16 + l15) * 512 + k0 + ks * 32 + q * 8,
                 bb + c * 512 + lane * 8);
        }
#pragma unroll
        for (int j = 0; j < 2; j++) {           // B chunks: 8 total, 2 per wave
            int c = w * 2 + j, nt = c >> 1, ks = c & 1;
            ld16(B + (size_t)(nt * 16 + l15) * 512 + k0 + ks * 32 + q * 8,
                 bb + 8192 + c * 512 + lane * 8);
        }
    };
    issue(0, lds);
    for (int ki = 0; ki < 8; ki++) {
        __syncthreads();                         // tile ki loaded; prev reads of other buf done
        if (ki < 7) issue((ki + 1) * 64, lds + ((ki + 1) & 1) * 12288);
        short* bb = lds + (ki & 1) * 12288;
        bf16x8 a[2][2], b[4][2];
#pragma unroll
        for (int mt = 0; mt < 2; mt++)
#pragma unroll
            for (int ks = 0; ks < 2; ks++)
                a[mt][ks] = *(bf16x8*)&bb[((w * 2 + mt) * 2 + ks) * 512 + lane * 8];
#pragma unroll
        for (int nt = 0; nt < 4; nt++)
#pragma unroll
            for (int ks = 0; ks < 2; ks++)
                b[nt][ks] = *(bf16x8*)&bb[8192 + (nt * 2 + ks) * 512 + lane * 8];
#pragma unroll
        for (int mt = 0; mt < 2; mt++)
#pragma unroll
            for (int nt = 0; nt < 4; nt++) {
                acc[mt][nt] = __builtin_amdgcn_mfma_f32_16x16x32_bf16(a[mt][0], b[nt][0], acc[mt][nt], 0, 0, 0);
                acc[mt][nt] = __builtin_amdgcn_mfma_f32_16x16x32_bf16(a[mt][1], b[nt][1], acc[mt][nt], 0, 0, 0);
            }
    }
}

// ---------------------------------------------------------------- Q/K projection
// mode(z): 0 -> q[bh][n][64], 1 -> k[bh][j][64]
__global__ __launch_bounds__(256, 3) void proj_qk(const short* __restrict__ xb,
                                                  const short* __restrict__ mb,
                                                  const short* __restrict__ wT,
                                                  short* __restrict__ qkv) {
    __shared__ __attribute__((aligned(16))) short lds[2 * 12288];
    int t = threadIdx.x, lane = t & 63, q = lane >> 4, l15 = lane & 15;
    int w = __builtin_amdgcn_readfirstlane(t >> 6);
    int mode = blockIdx.z;
    const short* A  = ((mode == 0) ? xb : mb) + (size_t)blockIdx.x * 128 * DIMK;
    const short* BT = wT + (size_t)mode * DIMK * DIMK + (size_t)blockIdx.y * 64 * DIMK;
    fx4 acc[2][4] = {};
    gemm_ml2(A, BT, lds, acc, w, lane, q, l15);

    int h = blockIdx.y;
    short* dst = qkv + (size_t)mode * MROWS * DIMK;
#pragma unroll
    for (int mt = 0; mt < 2; mt++)
#pragma unroll
        for (int nt = 0; nt < 4; nt++)
#pragma unroll
            for (int r = 0; r < 4; r++) {
                int gm = blockIdx.x * 128 + w * 32 + mt * 16 + q * 4 + r;
                int b = gm >> 11, n = gm & 2047;
                int d = nt * 16 + l15;
                dst[(((size_t)(b * 8 + h) * SEQ + n) << 6) + d] = f2bf(acc[mt][nt][r]);
            }
}

// ---------------------------------------------------------------- V^T projection
// vT[(b*8+h)*64+d][j] = sum_k m[b][j][k] Wv[k][h*64+d].  A = WvT (inner x 512), BT = mb rows.
// grid (4, 256): x over inner (128-tiles), y over 16384 n-rows (64-tiles).
__global__ __launch_bounds__(256, 3) void proj_vt(const short* __restrict__ mb,
                                                  const short* __restrict__ wTv,
                                                  short* __restrict__ vt) {
    __shared__ __attribute__((aligned(16))) short lds[2 * 12288];
    int t = threadIdx.x, lane = t & 63, q = lane >> 4, l15 = lane & 15;
    int w = __builtin_amdgcn_readfirstlane(t >> 6);
    const short* A  = wTv + (size_t)blockIdx.x * 128 * DIMK;
    const short* BT = mb + (size_t)blockIdx.y * 64 * DIMK;
    fx4 acc[2][4] = {};
    gemm_ml2(A, BT, lds, acc, w, lane, q, l15);

#pragma unroll
    for (int mt = 0; mt < 2; mt++)
#pragma unroll
        for (int nt = 0; nt < 4; nt++)
#pragma unroll
            for (int r = 0; r < 4; r++) {
                int gm = blockIdx.x * 128 + w * 32 + mt * 16 + q * 4 + r;  // inner = h*64+d
                int gn = blockIdx.y * 64 + nt * 16 + l15;                  // global n
                vt[((size_t)(gn >> 11) * 512 + gm) * SEQ + (gn & 2047)] = f2bf(acc[mt][nt][r]);
            }
}

// ---------------------------------------------------------------- output projection
__global__ __launch_bounds__(256, 3) void out_proj(const short* __restrict__ ob,
                                                   const short* __restrict__ woT,
                                                   const float* __restrict__ bo,
                                                   float* __restrict__ out) {
    __shared__ __attribute__((aligned(16))) short lds[2 * 12288];
    int t = threadIdx.x, lane = t & 63, q = lane >> 4, l15 = lane & 15;
    int w = __builtin_amdgcn_readfirstlane(t >> 6);
    const short* A  = ob + (size_t)blockIdx.x * 128 * DIMK;
    const short* BT = woT + (size_t)blockIdx.y * 64 * DIMK;
    fx4 acc[2][4] = {};
    gemm_ml2(A, BT, lds, acc, w, lane, q, l15);

#pragma unroll
    for (int mt = 0; mt < 2; mt++)
#pragma unroll
        for (int nt = 0; nt < 4; nt++) {
            int gn = blockIdx.y * 64 + nt * 16 + l15;
            float bias = bo[gn];
#pragma unroll
            for (int r = 0; r < 4; r++) {
                int gm = blockIdx.x * 128 + w * 32 + mt * 16 + q * 4 + r;
                out[(size_t)gm * DIMK + gn] = acc[mt][nt][r] + bias;
            }
        }
}

// ---------------------------------------------------------------- flash attention (S^T form)
// grid (16, 64). 4 waves; wave w owns q rows [i0+32w, i0+32w+32).
// Fragment-linear LDS, global_load_lds, double-buffered K/V, static softmax (no rescale).
__global__ __launch_bounds__(256, 3) void attn_kernel(const short* __restrict__ qg,
                                                      const short* __restrict__ kg,
                                                      const short* __restrict__ vg,
                                                      short* __restrict__ o) {
    // [buf0: K 4096 | V 4096][buf1: K | V][sQ 8192 shorts (aliased as per-wave sP)]
    __shared__ __attribute__((aligned(16))) short lds[2 * 8192 + 8192];
    int t = threadIdx.x, lane = t & 63, q = lane >> 4, l15 = lane & 15;
    int w = __builtin_amdgcn_readfirstlane(t >> 6);
    int bh = blockIdx.y;
    int i0 = blockIdx.x * 128;
    const short* qbh = qg + (size_t)bh * SEQ * DHEAD;
    const short* kbh = kg + (size_t)bh * SEQ * DHEAD;
    const short* vbh = vg + (size_t)bh * DHEAD * SEQ;
    short* sQ = lds + 16384;
    short* sP = sQ + w * 2048;   // wave-local 4KB, aliases this wave's own Q chunks

    auto issueKV = [&](int j0, short* bb) {
#pragma unroll
        for (int s = 0; s < 2; s++) {
            ld16(kbh + (size_t)(j0 + w * 16 + l15) * DHEAD + s * 32 + q * 8,
                 bb + (w * 2 + s) * 512 + lane * 8);
            ld16(vbh + (size_t)(w * 16 + l15) * SEQ + j0 + s * 32 + q * 8,
                 bb + 4096 + (w * 2 + s) * 512 + lane * 8);
        }
    };

    // prologue: Q chunks (wave-local) + K/V tile 0
#pragma unroll
    for (int j = 0; j < 4; j++) {
        int c = w * 4 + j, it_g = c >> 1, ks = c & 1;
        ld16(qbh + (size_t)(i0 + it_g * 16 + l15) * DHEAD + ks * 32 + q * 8,
             sQ + c * 512 + lane * 8);
    }
    issueKV(0, lds);
    __syncthreads();

    bf16x8 aq[2][2];
#pragma unroll
    for (int it = 0; it < 2; it++)
#pragma unroll
        for (int ks = 0; ks < 2; ks++)
            aq[it][ks] = *(bf16x8*)&sQ[((w * 2 + it) * 2 + ks) * 512 + lane * 8];

    float lsum[2] = {0.f, 0.f};
    fx4 oacc[2][4] = {};

    auto compute = [&](short* bb) {
        short* sKb = bb;
        short* sVb = bb + 4096;
        // S^T = K @ Q^T : lane holds S[i = it*16+l15][j = jt*16 + q*4 + r]
        fx4 s[2][4];
#pragma unroll
        for (int jt = 0; jt < 4; jt++) {
            bf16x8 ak0 = *(bf16x8*)&sKb[(jt * 2 + 0) * 512 + lane * 8];
            bf16x8 ak1 = *(bf16x8*)&sKb[(jt * 2 + 1) * 512 + lane * 8];
#pragma unroll
            for (int it = 0; it < 2; it++) {
                fx4 z = {0.f, 0.f, 0.f, 0.f};
                z = __builtin_amdgcn_mfma_f32_16x16x32_bf16(ak0, aq[it][0], z, 0, 0, 0);
                z = __builtin_amdgcn_mfma_f32_16x16x32_bf16(ak1, aq[it][1], z, 0, 0, 0);
                s[it][jt] = z;
            }
        }
        // static softmax numerator: p = exp2(s * scale*log2e); pack into sP (B-frag layout)
#pragma unroll
        for (int it = 0; it < 2; it++) {
#pragma unroll
            for (int jt = 0; jt < 4; jt++) {
                float p0 = __builtin_amdgcn_exp2f(s[it][jt][0] * SCALE_LOG2E);
                float p1 = __builtin_amdgcn_exp2f(s[it][jt][1] * SCALE_LOG2E);
                float p2 = __builtin_amdgcn_exp2f(s[it][jt][2] * SCALE_LOG2E);
                float p3 = __builtin_amdgcn_exp2f(s[it][jt][3] * SCALE_LOG2E);
                lsum[it] += (p0 + p1) + (p2 + p3);
                uint2 pv; pv.x = pk2bf(p0, p1); pv.y = pk2bf(p2, p3);
                *(uint2*)&sP[(it * 2 + (jt >> 1)) * 512 +
                             (((jt & 1) * 2 + (q >> 1)) * 16 + l15) * 8 + (q & 1) * 4] = pv;
            }
        }
        // P^T fragments (wave-local, no barrier)
        bf16x8 bp[2][2];
#pragma unroll
        for (int it = 0; it < 2; it++)
#pragma unroll
            for (int ks = 0; ks < 2; ks++)
                bp[it][ks] = *(bf16x8*)&sP[(it * 2 + ks) * 512 + lane * 8];
        // O^T += V^T @ P^T
#pragma unroll
        for (int dt = 0; dt < 4; dt++) {
            bf16x8 av0 = *(bf16x8*)&sVb[(dt * 2 + 0) * 512 + lane * 8];
            bf16x8 av1 = *(bf16x8*)&sVb[(dt * 2 + 1) * 512 + lane * 8];
#pragma unroll
            for (int it = 0; it < 2; it++) {
                oacc[it][dt] = __builtin_amdgcn_mfma_f32_16x16x32_bf16(av0, bp[it][0], oacc[it][dt], 0, 0, 0);
                oacc[it][dt] = __builtin_amdgcn_mfma_f32_16x16x32_bf16(av1, bp[it][1], oacc[it][dt], 0, 0, 0);
            }
        }
    };

    issueKV(64, lds + 8192);     // prefetch tile 1 while computing tile 0
    compute(lds);
    for (int ti = 1; ti < 32; ti++) {
        __syncthreads();         // tile ti loads done; all waves done reading buf[(ti+1)&1]
        if (ti < 31) issueKV((ti + 1) * 64, lds + ((ti + 1) & 1) * 8192);
        compute(lds + (ti & 1) * 8192);
    }

    // epilogue: row-sums via 2 cross-quad shuffles, then d-contiguous b64 stores
    int b = bh >> 3, h = bh & 7;
#pragma unroll
    for (int it = 0; it < 2; it++) {
        float l = lsum[it];
        l += __shfl_xor(l, 16);
        l += __shfl_xor(l, 32);
        float rl = 1.0f / l;
        int i = i0 + w * 32 + it * 16 + l15;
        size_t base = ((size_t)(b * SEQ + i) * DIMK) + h * DHEAD;
#pragma unroll
        for (int dt = 0; dt < 4; dt++) {
            uint2 pv;
            pv.x = pk2bf(oacc[it][dt][0] * rl, oacc[it][dt][1] * rl);
            pv.y = pk2bf(oacc[it][dt][2] * rl, oacc[it][dt][3] * rl);
            *(uint2*)&o[base + dt * 16 + q * 4] = pv;
        }
    }
}

// ---------------------------------------------------------------- launch
extern "C" void kernel_launch(void* const* d_in, const int* in_sizes, int n_in,
                              void* d_out, int out_size, void* d_ws, size_t ws_size,
                              hipStream_t stream) {
    const float* x  = (const float*)d_in[0];
    const float* m  = (const float*)d_in[1];
    const float* Wq = (const float*)d_in[2];
    const float* Wk = (const float*)d_in[3];
    const float* Wv = (const float*)d_in[4];
    const float* Wo = (const float*)d_in[5];
    const float* bo = (const float*)d_in[6];
    float* out = (float*)d_out;

    char* ws = (char*)d_ws;
    const size_t XB_BYTES = (size_t)MROWS * DIMK * 2;      // 16 MiB
    const size_t WT_ONE   = (size_t)DIMK * DIMK;           // elements per weight
    short* xb  = (short*)(ws);
    short* mb  = (short*)(ws + XB_BYTES);
    short* wT  = (short*)(ws + 2 * XB_BYTES);              // 4 x 512x512 bf16 = 2 MiB
    short* qkv = (short*)(ws + 2 * XB_BYTES + 4 * WT_ONE * 2);
    short* ob  = xb;   // xb dead after proj_qk; reuse as attention output

    const int CVT_BLOCKS = (MROWS * DIMK) / 4 / 256;       // 8192
    cvt_kernel<<<CVT_BLOCKS, 256, 0, stream>>>(x, xb);
    cvt_kernel<<<CVT_BLOCKS, 256, 0, stream>>>(m, mb);
    wtrans_kernel<<<dim3(16, 16, 4), dim3(32, 8), 0, stream>>>(Wq, Wk, Wv, Wo, wT);
    proj_qk<<<dim3(128, 8, 2), 256, 0, stream>>>(xb, mb, wT, qkv);
    proj_vt<<<dim3(4, 256), 256, 0, stream>>>(mb, wT + 2 * WT_ONE,
                                              qkv + 2 * (size_t)MROWS * DIMK);
    attn_kernel<<<dim3(SEQ / 128, BATCH * HEADS), 256, 0, stream>>>(
        qkv, qkv + (size_t)MROWS * DIMK, qkv + 2 * (size_t)MROWS * DIMK, ob);
    out_proj<<<dim3(128, 8), 256, 0, stream>>>(ob, wT + 3 * WT_ONE, bo, out);
}

// Round 5
// 294.382 us; speedup vs baseline: 1.0706x; 1.0706x over previous
//
#include <hip/hip_runtime.h>
#include <hip/hip_bf16.h>

// Problem constants
#define DIMK   512
#define HEADS  8
#define DHEAD  64
#define SEQ    2048
#define BATCH  8
#define MROWS  (BATCH*SEQ)      // 16384
#define SCALE_LOG2E (0.044194173824159216f * 1.44269504088896340736f) // 512^-0.5 * log2(e)

typedef float fx4   __attribute__((ext_vector_type(4)));
typedef short bf16x8 __attribute__((ext_vector_type(8)));
typedef short bf16x4 __attribute__((ext_vector_type(4)));

__device__ __forceinline__ short f2bf(float f) {
    union { float f; unsigned u; } x; x.f = f;
    unsigned r = (x.u + 0x7FFFu + ((x.u >> 16) & 1u)) >> 16;   // RNE
    return (short)r;
}

// pack two floats to two bf16 (round-half-up) in one dword via v_perm_b32
__device__ __forceinline__ unsigned pk2bf(float a, float b) {
    union { float f; unsigned u; } A, B; A.f = a; B.f = b;
    return __builtin_amdgcn_perm(B.u + 0x8000u, A.u + 0x8000u, 0x07060302u);
}

// async global->LDS, 16B per lane; LDS dest = wave-uniform base + lane*16
__device__ __forceinline__ void ld16(const short* g, short* l) {
    __builtin_amdgcn_global_load_lds(
        (const __attribute__((address_space(1))) unsigned int*)g,
        (__attribute__((address_space(3))) unsigned int*)l, 16, 0, 0);
}

#define MFMA(a, b, c) __builtin_amdgcn_mfma_f32_16x16x32_bf16(a, b, c, 0, 0, 0)

// ---------------------------------------------------------------- convert
__global__ __launch_bounds__(256) void cvt_kernel(const float* __restrict__ src,
                                                  short* __restrict__ dst) {
    int i = blockIdx.x * 256 + threadIdx.x;
    float4 v = ((const float4*)src)[i];
    bf16x4 o; o.x = f2bf(v.x); o.y = f2bf(v.y); o.z = f2bf(v.z); o.w = f2bf(v.w);
    ((bf16x4*)dst)[i] = o;
}

// ------------------------------------------------- weight transpose W[k][n] -> WT[n][k] bf16
__global__ __launch_bounds__(256) void wtrans_kernel(const float* __restrict__ Wq,
                                                     const float* __restrict__ Wk,
                                                     const float* __restrict__ Wv,
                                                     const float* __restrict__ Wo,
                                                     short* __restrict__ wT) {
    __shared__ float tile[32][33];
    const float* W = (blockIdx.z == 0) ? Wq : (blockIdx.z == 1) ? Wk
                   : (blockIdx.z == 2) ? Wv : Wo;
    short* dst = wT + (size_t)blockIdx.z * DIMK * DIMK;
    int n0 = blockIdx.x * 32, k0 = blockIdx.y * 32;
    int tx = threadIdx.x, ty = threadIdx.y;          // (32,8)
#pragma unroll
    for (int i = 0; i < 32; i += 8)
        tile[ty + i][tx] = W[(size_t)(k0 + ty + i) * DIMK + n0 + tx];
    __syncthreads();
#pragma unroll
    for (int i = 0; i < 32; i += 8)
        dst[(size_t)(n0 + ty + i) * DIMK + k0 + tx] = f2bf(tile[tx][ty + i]);
}

// ---------------------------------------------------------------- GEMM mainloop (m97-verbatim)
// C(128x128) = A(128x512) @ BT(128x512)^T. BK=32, single 16KB LDS buffer,
// 2-barrier K-loop, global_load_lds width 16. Wave w owns rows [32w, 32w+32).
// lds: 8192 shorts (A: 8 chunks x 512, B: 8 chunks x 512).
__device__ __forceinline__ void gemm97(const short* __restrict__ A,
                                       const short* __restrict__ B,
                                       short* lds, fx4 acc[2][8],
                                       int w, int lane, int q, int l15) {
    short* sA = lds;
    short* sB = lds + 4096;
    for (int k0 = 0; k0 < DIMK; k0 += 32) {
        __syncthreads();                         // prior iter's fragment reads complete
#pragma unroll
        for (int j = 0; j < 2; j++) {            // A chunks: 8 total, 2 per wave
            int c = w * 2 + j;
            ld16(A + (size_t)(c * 16 + l15) * DIMK + k0 + q * 8, sA + c * 512 + lane * 8);
        }
#pragma unroll
        for (int j = 0; j < 2; j++) {            // B chunks: 8 total, 2 per wave
            int c = w * 2 + j;
            ld16(B + (size_t)(c * 16 + l15) * DIMK + k0 + q * 8, sB + c * 512 + lane * 8);
        }
        __syncthreads();                         // tile resident
        bf16x8 a0 = *(bf16x8*)&sA[(w * 2 + 0) * 512 + lane * 8];
        bf16x8 a1 = *(bf16x8*)&sA[(w * 2 + 1) * 512 + lane * 8];
#pragma unroll
        for (int nt = 0; nt < 8; nt++) {
            bf16x8 b = *(bf16x8*)&sB[nt * 512 + lane * 8];
            acc[0][nt] = MFMA(a0, b, acc[0][nt]);
            acc[1][nt] = MFMA(a1, b, acc[1][nt]);
        }
    }
}

// ---------------------------------------------------------------- Q/K projection
// grid (4, 128, 2): x = inner 128-col tile (fastest: A m-tile L2 reuse), y = m-tile, z = mode
__global__ __launch_bounds__(256, 3) void proj_qk(const short* __restrict__ xb,
                                                  const short* __restrict__ mb,
                                                  const short* __restrict__ wT,
                                                  short* __restrict__ qkv) {
    __shared__ __attribute__((aligned(16))) short lds[8192];
    int t = threadIdx.x, lane = t & 63, q = lane >> 4, l15 = lane & 15;
    int w = __builtin_amdgcn_readfirstlane(t >> 6);
    int mode = blockIdx.z;
    const short* A = ((mode == 0) ? xb : mb) + (size_t)blockIdx.y * 128 * DIMK;
    const short* B = wT + (size_t)mode * DIMK * DIMK + (size_t)blockIdx.x * 128 * DIMK;
    fx4 acc[2][8] = {};
    gemm97(A, B, lds, acc, w, lane, q, l15);

    short* dst = qkv + (size_t)mode * MROWS * DIMK;
#pragma unroll
    for (int mt = 0; mt < 2; mt++)
#pragma unroll
        for (int nt = 0; nt < 8; nt++) {
            int inner = blockIdx.x * 128 + nt * 16 + l15;
            int h = inner >> 6, d = inner & 63;
#pragma unroll
            for (int r = 0; r < 4; r++) {
                int gm = blockIdx.y * 128 + (w * 2 + mt) * 16 + q * 4 + r;
                int b = gm >> 11, n = gm & 2047;
                dst[(((size_t)(b * 8 + h) * SEQ + n) << 6) + d] = f2bf(acc[mt][nt][r]);
            }
        }
}

// ---------------------------------------------------------------- V^T projection
// vT[(b*8+h)*64+d][j]: A = WvT (inner x 512), B = mb rows. grid (4, 128): x = inner tile, y = n tile.
__global__ __launch_bounds__(256, 3) void proj_vt(const short* __restrict__ mb,
                                                  const short* __restrict__ wTv,
                                                  short* __restrict__ vt) {
    __shared__ __attribute__((aligned(16))) short lds[8192];
    int t = threadIdx.x, lane = t & 63, q = lane >> 4, l15 = lane & 15;
    int w = __builtin_amdgcn_readfirstlane(t >> 6);
    const short* A = wTv + (size_t)blockIdx.x * 128 * DIMK;
    const short* B = mb + (size_t)blockIdx.y * 128 * DIMK;
    fx4 acc[2][8] = {};
    gemm97(A, B, lds, acc, w, lane, q, l15);

#pragma unroll
    for (int mt = 0; mt < 2; mt++)
#pragma unroll
        for (int nt = 0; nt < 8; nt++) {
            int gn = blockIdx.y * 128 + nt * 16 + l15;     // global n
            size_t nb = (size_t)(gn >> 11) * 512;
#pragma unroll
            for (int r = 0; r < 4; r++) {
                int gm = blockIdx.x * 128 + (w * 2 + mt) * 16 + q * 4 + r;   // inner = h*64+d
                vt[(nb + gm) * SEQ + (gn & 2047)] = f2bf(acc[mt][nt][r]);
            }
        }
}

// ---------------------------------------------------------------- output projection
// grid (4, 128): x = out-col tile, y = m-tile
__global__ __launch_bounds__(256, 3) void out_proj(const short* __restrict__ ob,
                                                   const short* __restrict__ woT,
                                                   const float* __restrict__ bo,
                                                   float* __restrict__ out) {
    __shared__ __attribute__((aligned(16))) short lds[8192];
    int t = threadIdx.x, lane = t & 63, q = lane >> 4, l15 = lane & 15;
    int w = __builtin_amdgcn_readfirstlane(t >> 6);
    const short* A = ob + (size_t)blockIdx.y * 128 * DIMK;
    const short* B = woT + (size_t)blockIdx.x * 128 * DIMK;
    fx4 acc[2][8] = {};
    gemm97(A, B, lds, acc, w, lane, q, l15);

#pragma unroll
    for (int mt = 0; mt < 2; mt++)
#pragma unroll
        for (int nt = 0; nt < 8; nt++) {
            int gn = blockIdx.x * 128 + nt * 16 + l15;
            float bias = bo[gn];
#pragma unroll
            for (int r = 0; r < 4; r++) {
                int gm = blockIdx.y * 128 + (w * 2 + mt) * 16 + q * 4 + r;
                out[(size_t)gm * DIMK + gn] = acc[mt][nt][r] + bias;
            }
        }
}

// ---------------------------------------------------------------- flash attention (S^T form)
// grid (16, 64), 1024 blocks = fully resident at 4 blocks/CU (LDS 40960 B).
// Wave w owns q rows [i0+32w, i0+32w+32). Double-buffered K/V, static softmax.
__global__ __launch_bounds__(256, 4) void attn_kernel(const short* __restrict__ qg,
                                                      const short* __restrict__ kg,
                                                      const short* __restrict__ vg,
                                                      short* __restrict__ o) {
    // [buf0: K 4096 | V 4096][buf1: K | V][sP 4096 shorts = 1024/wave]
    __shared__ __attribute__((aligned(16))) short lds[2 * 8192 + 4096];
    int t = threadIdx.x, lane = t & 63, q = lane >> 4, l15 = lane & 15;
    int w = __builtin_amdgcn_readfirstlane(t >> 6);
    int bh = blockIdx.y;
    int i0 = blockIdx.x * 128;
    const short* qbh = qg + (size_t)bh * SEQ * DHEAD;
    const short* kbh = kg + (size_t)bh * SEQ * DHEAD;
    const short* vbh = vg + (size_t)bh * DHEAD * SEQ;
    short* sP = lds + 16384 + w * 1024;   // wave-local 2KB

    auto issueKV = [&](int j0, short* bb) {
#pragma unroll
        for (int s = 0; s < 2; s++) {
            ld16(kbh + (size_t)(j0 + w * 16 + l15) * DHEAD + s * 32 + q * 8,
                 bb + (w * 2 + s) * 512 + lane * 8);
            ld16(vbh + (size_t)(w * 16 + l15) * SEQ + j0 + s * 32 + q * 8,
                 bb + 4096 + (w * 2 + s) * 512 + lane * 8);
        }
    };

    // prologue: stage Q (128x64 = 16KB) through buf0, then reclaim buf0 for K/V
#pragma unroll
    for (int j = 0; j < 4; j++) {
        int c = w * 4 + j;                // chunk c = w*4 + it*2 + ks
        int it_g = (c >> 1) & 3, dummy = 0; (void)dummy;
        ld16(qbh + (size_t)(i0 + (c >> 1) * 16 + l15) * DHEAD + (c & 1) * 32 + q * 8,
             lds + c * 512 + lane * 8);
    }
    __syncthreads();                      // Q resident
    bf16x8 aq[2][2];
#pragma unroll
    for (int it = 0; it < 2; it++)
#pragma unroll
        for (int ks = 0; ks < 2; ks++)
            aq[it][ks] = *(bf16x8*)&lds[(w * 4 + it * 2 + ks) * 512 + lane * 8];
    __syncthreads();                      // all waves' Q fragment reads done
    issueKV(0, lds);                      // tile 0 -> buf0 (overwrites Q)
    issueKV(64, lds + 8192);              // tile 1 -> buf1
    __syncthreads();                      // tiles 0,1 resident

    float lsum[2] = {0.f, 0.f};
    fx4 oacc[2][4] = {};

    auto compute = [&](short* bb) {
        short* sKb = bb;
        short* sVb = bb + 4096;
        // S^T = K @ Q^T : lane holds S[i = it*16+l15][j = jt*16 + q*4 + r]
        fx4 s[2][4];
#pragma unroll
        for (int jt = 0; jt < 4; jt++) {
            bf16x8 ak0 = *(bf16x8*)&sKb[(jt * 2 + 0) * 512 + lane * 8];
            bf16x8 ak1 = *(bf16x8*)&sKb[(jt * 2 + 1) * 512 + lane * 8];
#pragma unroll
            for (int it = 0; it < 2; it++) {
                fx4 z = {0.f, 0.f, 0.f, 0.f};
                z = MFMA(ak0, aq[it][0], z);
                z = MFMA(ak1, aq[it][1], z);
                s[it][jt] = z;
            }
        }
        // static softmax numerator; P round-trip through wave-local sP (16 rows at a time)
        bf16x8 bp[2][2];
#pragma unroll
        for (int it = 0; it < 2; it++) {
#pragma unroll
            for (int jt = 0; jt < 4; jt++) {
                float p0 = __builtin_amdgcn_exp2f(s[it][jt][0] * SCALE_LOG2E);
                float p1 = __builtin_amdgcn_exp2f(s[it][jt][1] * SCALE_LOG2E);
                float p2 = __builtin_amdgcn_exp2f(s[it][jt][2] * SCALE_LOG2E);
                float p3 = __builtin_amdgcn_exp2f(s[it][jt][3] * SCALE_LOG2E);
                lsum[it] += (p0 + p1) + (p2 + p3);
                uint2 pv; pv.x = pk2bf(p0, p1); pv.y = pk2bf(p2, p3);
                *(uint2*)&sP[(jt >> 1) * 512 +
                             (((jt & 1) * 2 + (q >> 1)) * 16 + l15) * 8 + (q & 1) * 4] = pv;
            }
            // wave-local DS ops are in-order: reads see the writes above; next it overwrites safely
            bp[it][0] = *(bf16x8*)&sP[lane * 8];
            bp[it][1] = *(bf16x8*)&sP[512 + lane * 8];
        }
        // O^T += V^T @ P^T
#pragma unroll
        for (int dt = 0; dt < 4; dt++) {
            bf16x8 av0 = *(bf16x8*)&sVb[(dt * 2 + 0) * 512 + lane * 8];
            bf16x8 av1 = *(bf16x8*)&sVb[(dt * 2 + 1) * 512 + lane * 8];
#pragma unroll
            for (int it = 0; it < 2; it++) {
                oacc[it][dt] = MFMA(av0, bp[it][0], oacc[it][dt]);
                oacc[it][dt] = MFMA(av1, bp[it][1], oacc[it][dt]);
            }
        }
    };

    compute(lds);                         // tile 0
    for (int ti = 1; ti < 32; ti++) {
        __syncthreads();                  // tile ti resident; buf[(ti+1)&1] reads done
        if (ti < 31) issueKV((ti + 1) * 64, lds + ((ti + 1) & 1) * 8192);
        compute(lds + (ti & 1) * 8192);
    }

    // epilogue: row-sums via 2 cross-quad shuffles, then d-contiguous b64 stores
    int b = bh >> 3, h = bh & 7;
#pragma unroll
    for (int it = 0; it < 2; it++) {
        float l = lsum[it];
        l += __shfl_xor(l, 16);
        l += __shfl_xor(l, 32);
        float rl = 1.0f / l;
        int i = i0 + w * 32 + it * 16 + l15;
        size_t base = ((size_t)(b * SEQ + i) * DIMK) + h * DHEAD;
#pragma unroll
        for (int dt = 0; dt < 4; dt++) {
            uint2 pv;
            pv.x = pk2bf(oacc[it][dt][0] * rl, oacc[it][dt][1] * rl);
            pv.y = pk2bf(oacc[it][dt][2] * rl, oacc[it][dt][3] * rl);
            *(uint2*)&o[base + dt * 16 + q * 4] = pv;
        }
    }
}

// ---------------------------------------------------------------- launch
extern "C" void kernel_launch(void* const* d_in, const int* in_sizes, int n_in,
                              void* d_out, int out_size, void* d_ws, size_t ws_size,
                              hipStream_t stream) {
    const float* x  = (const float*)d_in[0];
    const float* m  = (const float*)d_in[1];
    const float* Wq = (const float*)d_in[2];
    const float* Wk = (const float*)d_in[3];
    const float* Wv = (const float*)d_in[4];
    const float* Wo = (const float*)d_in[5];
    const float* bo = (const float*)d_in[6];
    float* out = (float*)d_out;

    char* ws = (char*)d_ws;
    const size_t XB_BYTES = (size_t)MROWS * DIMK * 2;      // 16 MiB
    const size_t WT_ONE   = (size_t)DIMK * DIMK;           // elements per weight
    short* xb  = (short*)(ws);
    short* mb  = (short*)(ws + XB_BYTES);
    short* wT  = (short*)(ws + 2 * XB_BYTES);              // 4 x 512x512 bf16 = 2 MiB
    short* qkv = (short*)(ws + 2 * XB_BYTES + 4 * WT_ONE * 2);
    short* ob  = xb;   // xb dead after proj_qk; reuse as attention output

    const int CVT_BLOCKS = (MROWS * DIMK) / 4 / 256;       // 8192
    cvt_kernel<<<CVT_BLOCKS, 256, 0, stream>>>(x, xb);
    cvt_kernel<<<CVT_BLOCKS, 256, 0, stream>>>(m, mb);
    wtrans_kernel<<<dim3(16, 16, 4), dim3(32, 8), 0, stream>>>(Wq, Wk, Wv, Wo, wT);
    proj_qk<<<dim3(4, 128, 2), 256, 0, stream>>>(xb, mb, wT, qkv);
    proj_vt<<<dim3(4, 128), 256, 0, stream>>>(mb, wT + 2 * WT_ONE,
                                              qkv + 2 * (size_t)MROWS * DIMK);
    attn_kernel<<<dim3(SEQ / 128, BATCH * HEADS), 256, 0, stream>>>(
        qkv, qkv + (size_t)MROWS * DIMK, qkv + 2 * (size_t)MROWS * DIMK, ob);
    out_proj<<<dim3(4, 128), 256, 0, stream>>>(ob, wT + 3 * WT_ONE, bo, out);
}

// Round 6
// 288.752 us; speedup vs baseline: 1.0915x; 1.0195x over previous
//
#include <hip/hip_runtime.h>
#include <hip/hip_bf16.h>

// Problem constants
#define DIMK   512
#define HEADS  8
#define DHEAD  64
#define SEQ    2048
#define BATCH  8
#define MROWS  (BATCH*SEQ)      // 16384
#define SCALE_LOG2E (0.044194173824159216f * 1.44269504088896340736f) // 512^-0.5 * log2(e)

typedef float fx4   __attribute__((ext_vector_type(4)));
typedef short bf16x8 __attribute__((ext_vector_type(8)));
typedef short bf16x4 __attribute__((ext_vector_type(4)));

__device__ __forceinline__ short f2bf(float f) {
    union { float f; unsigned u; } x; x.f = f;
    unsigned r = (x.u + 0x7FFFu + ((x.u >> 16) & 1u)) >> 16;   // RNE
    return (short)r;
}

// pack two floats to two bf16 (round-half-up) in one dword via v_perm_b32
__device__ __forceinline__ unsigned pk2bf(float a, float b) {
    union { float f; unsigned u; } A, B; A.f = a; B.f = b;
    return __builtin_amdgcn_perm(B.u + 0x8000u, A.u + 0x8000u, 0x07060302u);
}

// async global->LDS, 16B per lane; LDS dest = wave-uniform base + lane*16
__device__ __forceinline__ void ld16(const short* g, short* l) {
    __builtin_amdgcn_global_load_lds(
        (const __attribute__((address_space(1))) unsigned int*)g,
        (__attribute__((address_space(3))) unsigned int*)l, 16, 0, 0);
}

#define MFMA(a, b, c) __builtin_amdgcn_mfma_f32_16x16x32_bf16(a, b, c, 0, 0, 0)

// ---------------------------------------------------------------- convert
__global__ __launch_bounds__(256) void cvt_kernel(const float* __restrict__ src,
                                                  short* __restrict__ dst) {
    int i = blockIdx.x * 256 + threadIdx.x;
    float4 v = ((const float4*)src)[i];
    bf16x4 o; o.x = f2bf(v.x); o.y = f2bf(v.y); o.z = f2bf(v.z); o.w = f2bf(v.w);
    ((bf16x4*)dst)[i] = o;
}

// ------------------------------------------------- weight transpose W[k][n] -> WT[n][k] bf16
__global__ __launch_bounds__(256) void wtrans_kernel(const float* __restrict__ Wq,
                                                     const float* __restrict__ Wk,
                                                     const float* __restrict__ Wv,
                                                     const float* __restrict__ Wo,
                                                     short* __restrict__ wT) {
    __shared__ float tile[32][33];
    const float* W = (blockIdx.z == 0) ? Wq : (blockIdx.z == 1) ? Wk
                   : (blockIdx.z == 2) ? Wv : Wo;
    short* dst = wT + (size_t)blockIdx.z * DIMK * DIMK;
    int n0 = blockIdx.x * 32, k0 = blockIdx.y * 32;
    int tx = threadIdx.x, ty = threadIdx.y;          // (32,8)
#pragma unroll
    for (int i = 0; i < 32; i += 8)
        tile[ty + i][tx] = W[(size_t)(k0 + ty + i) * DIMK + n0 + tx];
    __syncthreads();
#pragma unroll
    for (int i = 0; i < 32; i += 8)
        dst[(size_t)(n0 + ty + i) * DIMK + k0 + tx] = f2bf(tile[tx][ty + i]);
}

// ---------------------------------------------------------------- GEMM mainloop (m97-style)
// Stages A(128x512 act rows) and B(128x512 weight rows), BK=32, 16KB LDS, 2-barrier loop.
// OWN_B=0: acc[mt][nt] = D[act][weight] (lane: 4 consecutive act rows)
// OWN_B=1: acc[mi][nj] = D[weight][act] (lane: 4 consecutive weight rows = inner cols)
template<int OWN_B>
__device__ __forceinline__ void gemm97(const short* __restrict__ A,
                                       const short* __restrict__ B,
                                       short* lds, fx4 acc[2][8],
                                       int w, int lane, int q, int l15) {
    short* sA = lds;
    short* sB = lds + 4096;
    for (int k0 = 0; k0 < DIMK; k0 += 32) {
        __syncthreads();                         // prior iter's fragment reads complete
#pragma unroll
        for (int j = 0; j < 2; j++) {
            int c = w * 2 + j;
            ld16(A + (size_t)(c * 16 + l15) * DIMK + k0 + q * 8, sA + c * 512 + lane * 8);
            ld16(B + (size_t)(c * 16 + l15) * DIMK + k0 + q * 8, sB + c * 512 + lane * 8);
        }
        __syncthreads();                         // tile resident
        short* sOwn = OWN_B ? sB : sA;
        short* sAll = OWN_B ? sA : sB;
        bf16x8 o0 = *(bf16x8*)&sOwn[(w * 2 + 0) * 512 + lane * 8];
        bf16x8 o1 = *(bf16x8*)&sOwn[(w * 2 + 1) * 512 + lane * 8];
#pragma unroll
        for (int nt = 0; nt < 8; nt++) {
            bf16x8 f = *(bf16x8*)&sAll[nt * 512 + lane * 8];
            acc[0][nt] = MFMA(o0, f, acc[0][nt]);
            acc[1][nt] = MFMA(o1, f, acc[1][nt]);
        }
    }
}

// ---------------------------------------------------------------- Q/K projection (transposed orient)
// grid (4, 128, 2): x = inner tile, y = n tile, z = mode (0=q prescaled, 1=k)
// D[inner][n]: lane holds 4 consecutive inner (d) at fixed n -> b64 stores into [bh][n][d].
__global__ __launch_bounds__(256, 3) void proj_qk(const short* __restrict__ xb,
                                                  const short* __restrict__ mb,
                                                  const short* __restrict__ wT,
                                                  short* __restrict__ qkv) {
    __shared__ __attribute__((aligned(16))) short lds[8192];
    int t = threadIdx.x, lane = t & 63, q = lane >> 4, l15 = lane & 15;
    int w = __builtin_amdgcn_readfirstlane(t >> 6);
    int mode = blockIdx.z;
    const short* A = ((mode == 0) ? xb : mb) + (size_t)blockIdx.y * 128 * DIMK;
    const short* B = wT + (size_t)mode * DIMK * DIMK + (size_t)blockIdx.x * 128 * DIMK;
    fx4 acc[2][8] = {};
    gemm97<1>(A, B, lds, acc, w, lane, q, l15);

    float sc = (mode == 0) ? (float)SCALE_LOG2E : 1.0f;   // fold softmax scale into q
    short* dst = qkv + (size_t)mode * MROWS * DIMK;
#pragma unroll
    for (int mi = 0; mi < 2; mi++) {
        int inner0 = blockIdx.x * 128 + w * 32 + mi * 16 + q * 4;
        int h = inner0 >> 6, d0 = inner0 & 63;
#pragma unroll
        for (int nj = 0; nj < 8; nj++) {
            int gn = blockIdx.y * 128 + nj * 16 + l15;
            int b = gn >> 11, n = gn & 2047;
            uint2 pv;
            pv.x = pk2bf(acc[mi][nj][0] * sc, acc[mi][nj][1] * sc);
            pv.y = pk2bf(acc[mi][nj][2] * sc, acc[mi][nj][3] * sc);
            *(uint2*)&dst[(((size_t)(b * 8 + h) * SEQ + n) << 6) + d0] = pv;
        }
    }
}

// ---------------------------------------------------------------- V^T projection (original orient)
// grid (4, 128): x = inner tile, y = n tile. D[n][inner]: lane holds 4 consecutive n (j)
// at fixed inner -> b64 stores into vT[bh*64+d][j].
__global__ __launch_bounds__(256, 3) void proj_v(const short* __restrict__ mb,
                                                 const short* __restrict__ wTv,
                                                 short* __restrict__ vt) {
    __shared__ __attribute__((aligned(16))) short lds[8192];
    int t = threadIdx.x, lane = t & 63, q = lane >> 4, l15 = lane & 15;
    int w = __builtin_amdgcn_readfirstlane(t >> 6);
    const short* A = mb + (size_t)blockIdx.y * 128 * DIMK;
    const short* B = wTv + (size_t)blockIdx.x * 128 * DIMK;
    fx4 acc[2][8] = {};
    gemm97<0>(A, B, lds, acc, w, lane, q, l15);

#pragma unroll
    for (int mt = 0; mt < 2; mt++) {
        int gm0 = blockIdx.y * 128 + w * 32 + mt * 16 + q * 4;  // global act row base
        int b = gm0 >> 11, j0 = gm0 & 2047;
#pragma unroll
        for (int nt = 0; nt < 8; nt++) {
            int inner = blockIdx.x * 128 + nt * 16 + l15;       // h*64+d
            uint2 pv;
            pv.x = pk2bf(acc[mt][nt][0], acc[mt][nt][1]);
            pv.y = pk2bf(acc[mt][nt][2], acc[mt][nt][3]);
            *(uint2*)&vt[((size_t)b * 512 + inner) * SEQ + j0] = pv;
        }
    }
}

// ---------------------------------------------------------------- output projection (transposed)
// grid (4, 128): x = out-col tile, y = m tile. Lane holds 4 consecutive out-cols -> float4 stores.
__global__ __launch_bounds__(256, 3) void out_proj(const short* __restrict__ ob,
                                                   const short* __restrict__ woT,
                                                   const float* __restrict__ bo,
                                                   float* __restrict__ out) {
    __shared__ __attribute__((aligned(16))) short lds[8192];
    int t = threadIdx.x, lane = t & 63, q = lane >> 4, l15 = lane & 15;
    int w = __builtin_amdgcn_readfirstlane(t >> 6);
    const short* A = ob + (size_t)blockIdx.y * 128 * DIMK;
    const short* B = woT + (size_t)blockIdx.x * 128 * DIMK;
    fx4 acc[2][8] = {};
    gemm97<1>(A, B, lds, acc, w, lane, q, l15);

#pragma unroll
    for (int mi = 0; mi < 2; mi++) {
        int gn0 = blockIdx.x * 128 + w * 32 + mi * 16 + q * 4;  // out col base
        float4 b4 = *(const float4*)&bo[gn0];
#pragma unroll
        for (int nj = 0; nj < 8; nj++) {
            int n = blockIdx.y * 128 + nj * 16 + l15;           // act row
            float4 v;
            v.x = acc[mi][nj][0] + b4.x;
            v.y = acc[mi][nj][1] + b4.y;
            v.z = acc[mi][nj][2] + b4.z;
            v.w = acc[mi][nj][3] + b4.w;
            *(float4*)&out[(size_t)n * DIMK + gn0] = v;
        }
    }
}

// ---------------------------------------------------------------- flash attention (S^T form)
// grid (16, 64), 1024 blocks, 4 blocks/CU (LDS 36864 B). Wave w owns q rows [i0+32w,+32).
// Q pre-scaled by SCALE*log2e at projection. Row-sums via ones-MFMA. Static softmax.
__global__ __launch_bounds__(256, 4) void attn_kernel(const short* __restrict__ qg,
                                                      const short* __restrict__ kg,
                                                      const short* __restrict__ vg,
                                                      short* __restrict__ o) {
    // [buf0: K 4096 | V 4096][buf1: K | V][sP 2048 shorts = 512/wave]
    __shared__ __attribute__((aligned(16))) short lds[2 * 8192 + 2048];
    int t = threadIdx.x, lane = t & 63, q = lane >> 4, l15 = lane & 15;
    int w = __builtin_amdgcn_readfirstlane(t >> 6);
    int bh = blockIdx.y;
    int i0 = blockIdx.x * 128;
    const short* qbh = qg + (size_t)bh * SEQ * DHEAD;
    const short* kbh = kg + (size_t)bh * SEQ * DHEAD;
    const short* vbh = vg + (size_t)bh * DHEAD * SEQ;
    short* sP = lds + 16384 + w * 512;    // wave-local 1KB

    const bf16x8 ones = {0x3F80, 0x3F80, 0x3F80, 0x3F80, 0x3F80, 0x3F80, 0x3F80, 0x3F80};

    auto issueKV = [&](int j0, short* bb) {
#pragma unroll
        for (int s = 0; s < 2; s++) {
            ld16(kbh + (size_t)(j0 + w * 16 + l15) * DHEAD + s * 32 + q * 8,
                 bb + (w * 2 + s) * 512 + lane * 8);
            ld16(vbh + (size_t)(w * 16 + l15) * SEQ + j0 + s * 32 + q * 8,
                 bb + 4096 + (w * 2 + s) * 512 + lane * 8);
        }
    };

    // prologue: stage Q (128x64 = 16KB) through buf0, then reclaim buf0 for K/V
#pragma unroll
    for (int j = 0; j < 4; j++) {
        int c = w * 4 + j;                // chunk c = w*4 + it*2 + ks
        ld16(qbh + (size_t)(i0 + (c >> 1) * 16 + l15) * DHEAD + (c & 1) * 32 + q * 8,
             lds + c * 512 + lane * 8);
    }
    __syncthreads();                      // Q resident
    bf16x8 aq[2][2];
#pragma unroll
    for (int it = 0; it < 2; it++)
#pragma unroll
        for (int ks = 0; ks < 2; ks++)
            aq[it][ks] = *(bf16x8*)&lds[(w * 4 + it * 2 + ks) * 512 + lane * 8];
    __syncthreads();                      // all waves' Q fragment reads done
    issueKV(0, lds);                      // tile 0 -> buf0 (overwrites Q)
    issueKV(64, lds + 8192);              // tile 1 -> buf1
    __syncthreads();                      // tiles 0,1 resident

    fx4 oacc[2][4] = {};
    fx4 sacc[2] = {};                     // P row-sums via ones-MFMA

    auto compute = [&](short* bb) {
        short* sKb = bb;
        short* sVb = bb + 4096;
        // S^T = K @ Q^T : lane holds S[i = it*16+l15][j = jt*16 + q*4 + r], already x scale*log2e
        fx4 s[2][4];
#pragma unroll
        for (int jt = 0; jt < 4; jt++) {
            bf16x8 ak0 = *(bf16x8*)&sKb[(jt * 2 + 0) * 512 + lane * 8];
            bf16x8 ak1 = *(bf16x8*)&sKb[(jt * 2 + 1) * 512 + lane * 8];
#pragma unroll
            for (int it = 0; it < 2; it++) {
                fx4 z = {0.f, 0.f, 0.f, 0.f};
                z = MFMA(ak0, aq[it][0], z);
                z = MFMA(ak1, aq[it][1], z);
                s[it][jt] = z;
            }
        }
        // static softmax numerator; P round-trip per (it,ks) through 1KB wave-local sP
        bf16x8 bp[2][2];
#pragma unroll
        for (int it = 0; it < 2; it++) {
#pragma unroll
            for (int ks = 0; ks < 2; ks++) {
#pragma unroll
                for (int h2 = 0; h2 < 2; h2++) {
                    int jt = ks * 2 + h2;
                    float p0 = __builtin_amdgcn_exp2f(s[it][jt][0]);
                    float p1 = __builtin_amdgcn_exp2f(s[it][jt][1]);
                    float p2 = __builtin_amdgcn_exp2f(s[it][jt][2]);
                    float p3 = __builtin_amdgcn_exp2f(s[it][jt][3]);
                    uint2 pv; pv.x = pk2bf(p0, p1); pv.y = pk2bf(p2, p3);
                    *(uint2*)&sP[((h2 * 2 + (q >> 1)) * 16 + l15) * 8 + (q & 1) * 4] = pv;
                }
                // wave-local DS ops are in-order: read sees the two writes above
                bp[it][ks] = *(bf16x8*)&sP[lane * 8];
                sacc[it] = MFMA(ones, bp[it][ks], sacc[it]);   // row-sums, no VALU adds
            }
        }
        // O^T += V^T @ P^T
#pragma unroll
        for (int dt = 0; dt < 4; dt++) {
            bf16x8 av0 = *(bf16x8*)&sVb[(dt * 2 + 0) * 512 + lane * 8];
            bf16x8 av1 = *(bf16x8*)&sVb[(dt * 2 + 1) * 512 + lane * 8];
#pragma unroll
            for (int it = 0; it < 2; it++) {
                oacc[it][dt] = MFMA(av0, bp[it][0], oacc[it][dt]);
                oacc[it][dt] = MFMA(av1, bp[it][1], oacc[it][dt]);
            }
        }
    };

    compute(lds);                         // tile 0
    for (int ti = 1; ti < 32; ti++) {
        __syncthreads();                  // tile ti resident; buf[(ti+1)&1] reads done
        if (ti < 31) issueKV((ti + 1) * 64, lds + ((ti + 1) & 1) * 8192);
        compute(lds + (ti & 1) * 8192);
    }

    // epilogue: lane already holds its row-sum in sacc[it][0] (all r equal, i = it*16+l15)
    int b = bh >> 3, h = bh & 7;
#pragma unroll
    for (int it = 0; it < 2; it++) {
        float rl = 1.0f / sacc[it][0];
        int i = i0 + w * 32 + it * 16 + l15;
        size_t base = ((size_t)(b * SEQ + i) * DIMK) + h * DHEAD;
#pragma unroll
        for (int dt = 0; dt < 4; dt++) {
            uint2 pv;
            pv.x = pk2bf(oacc[it][dt][0] * rl, oacc[it][dt][1] * rl);
            pv.y = pk2bf(oacc[it][dt][2] * rl, oacc[it][dt][3] * rl);
            *(uint2*)&o[base + dt * 16 + q * 4] = pv;
        }
    }
}

// ---------------------------------------------------------------- launch
extern "C" void kernel_launch(void* const* d_in, const int* in_sizes, int n_in,
                              void* d_out, int out_size, void* d_ws, size_t ws_size,
                              hipStream_t stream) {
    const float* x  = (const float*)d_in[0];
    const float* m  = (const float*)d_in[1];
    const float* Wq = (const float*)d_in[2];
    const float* Wk = (const float*)d_in[3];
    const float* Wv = (const float*)d_in[4];
    const float* Wo = (const float*)d_in[5];
    const float* bo = (const float*)d_in[6];
    float* out = (float*)d_out;

    char* ws = (char*)d_ws;
    const size_t XB_BYTES = (size_t)MROWS * DIMK * 2;      // 16 MiB
    const size_t WT_ONE   = (size_t)DIMK * DIMK;           // elements per weight
    short* xb  = (short*)(ws);
    short* mb  = (short*)(ws + XB_BYTES);
    short* wT  = (short*)(ws + 2 * XB_BYTES);              // 4 x 512x512 bf16 = 2 MiB
    short* qkv = (short*)(ws + 2 * XB_BYTES + 4 * WT_ONE * 2);
    short* ob  = xb;   // xb dead after proj_qk; reuse as attention output

    const int CVT_BLOCKS = (MROWS * DIMK) / 4 / 256;       // 8192
    cvt_kernel<<<CVT_BLOCKS, 256, 0, stream>>>(x, xb);
    cvt_kernel<<<CVT_BLOCKS, 256, 0, stream>>>(m, mb);
    wtrans_kernel<<<dim3(16, 16, 4), dim3(32, 8), 0, stream>>>(Wq, Wk, Wv, Wo, wT);
    proj_qk<<<dim3(4, 128, 2), 256, 0, stream>>>(xb, mb, wT, qkv);
    proj_v<<<dim3(4, 128), 256, 0, stream>>>(mb, wT + 2 * WT_ONE,
                                             qkv + 2 * (size_t)MROWS * DIMK);
    attn_kernel<<<dim3(SEQ / 128, BATCH * HEADS), 256, 0, stream>>>(
        qkv, qkv + (size_t)MROWS * DIMK, qkv + 2 * (size_t)MROWS * DIMK, ob);
    out_proj<<<dim3(4, 128), 256, 0, stream>>>(ob, wT + 3 * WT_ONE, bo, out);
}

// Round 7
// 275.314 us; speedup vs baseline: 1.1447x; 1.0488x over previous
//
#include <hip/hip_runtime.h>
#include <hip/hip_bf16.h>

// Problem constants
#define DIMK   512
#define HEADS  8
#define DHEAD  64
#define SEQ    2048
#define BATCH  8
#define MROWS  (BATCH*SEQ)      // 16384
#define SCALE_LOG2E (0.044194173824159216f * 1.44269504088896340736f) // 512^-0.5 * log2(e)

typedef float fx4   __attribute__((ext_vector_type(4)));
typedef short bf16x8 __attribute__((ext_vector_type(8)));
typedef short bf16x4 __attribute__((ext_vector_type(4)));

__device__ __forceinline__ short f2bf(float f) {
    union { float f; unsigned u; } x; x.f = f;
    unsigned r = (x.u + 0x7FFFu + ((x.u >> 16) & 1u)) >> 16;   // RNE
    return (short)r;
}

// pack two floats to two bf16 (round-half-up) in one dword via v_perm_b32
__device__ __forceinline__ unsigned pk2bf(float a, float b) {
    union { float f; unsigned u; } A, B; A.f = a; B.f = b;
    return __builtin_amdgcn_perm(B.u + 0x8000u, A.u + 0x8000u, 0x07060302u);
}

// async global->LDS, 16B per lane; LDS dest = wave-uniform base + lane*16
__device__ __forceinline__ void ld16(const short* g, short* l) {
    __builtin_amdgcn_global_load_lds(
        (const __attribute__((address_space(1))) unsigned int*)g,
        (__attribute__((address_space(3))) unsigned int*)l, 16, 0, 0);
}

#define MFMA(a, b, c) __builtin_amdgcn_mfma_f32_16x16x32_bf16(a, b, c, 0, 0, 0)

// ---------------------------------------------------------------- convert (x and m fused)
__global__ __launch_bounds__(256) void cvt_kernel(const float* __restrict__ x,
                                                  const float* __restrict__ m,
                                                  short* __restrict__ xb,
                                                  short* __restrict__ mb) {
    int bid = blockIdx.x;
    const float* src = (bid < 8192) ? x : m;
    short* dst = (bid < 8192) ? xb : mb;
    int i = (bid & 8191) * 256 + threadIdx.x;
    float4 v = ((const float4*)src)[i];
    bf16x4 o; o.x = f2bf(v.x); o.y = f2bf(v.y); o.z = f2bf(v.z); o.w = f2bf(v.w);
    ((bf16x4*)dst)[i] = o;
}

// ------------------------------------------------- weight transpose W[k][n] -> WT[n][k] bf16
__global__ __launch_bounds__(256) void wtrans_kernel(const float* __restrict__ Wq,
                                                     const float* __restrict__ Wk,
                                                     const float* __restrict__ Wv,
                                                     const float* __restrict__ Wo,
                                                     short* __restrict__ wT) {
    __shared__ float tile[32][33];
    const float* W = (blockIdx.z == 0) ? Wq : (blockIdx.z == 1) ? Wk
                   : (blockIdx.z == 2) ? Wv : Wo;
    short* dst = wT + (size_t)blockIdx.z * DIMK * DIMK;
    int n0 = blockIdx.x * 32, k0 = blockIdx.y * 32;
    int tx = threadIdx.x, ty = threadIdx.y;          // (32,8)
#pragma unroll
    for (int i = 0; i < 32; i += 8)
        tile[ty + i][tx] = W[(size_t)(k0 + ty + i) * DIMK + n0 + tx];
    __syncthreads();
#pragma unroll
    for (int i = 0; i < 32; i += 8)
        dst[(size_t)(n0 + ty + i) * DIMK + k0 + tx] = f2bf(tile[tx][ty + i]);
}

// ---------------------------------------------------------------- GEMM mainloop (m97-style)
// Stages A(128x512 act rows) and B(128x512 weight rows), BK=32, 16KB LDS, 2-barrier loop.
// OWN_B=0: acc[mt][nt] = D[act][weight] (lane: 4 consecutive act rows)
// OWN_B=1: acc[mi][nj] = D[weight][act] (lane: 4 consecutive weight rows = inner cols)
template<int OWN_B>
__device__ __forceinline__ void gemm97(const short* __restrict__ A,
                                       const short* __restrict__ B,
                                       short* lds, fx4 acc[2][8],
                                       int w, int lane, int q, int l15) {
    short* sA = lds;
    short* sB = lds + 4096;
    for (int k0 = 0; k0 < DIMK; k0 += 32) {
        __syncthreads();                         // prior iter's fragment reads complete
#pragma unroll
        for (int j = 0; j < 2; j++) {
            int c = w * 2 + j;
            ld16(A + (size_t)(c * 16 + l15) * DIMK + k0 + q * 8, sA + c * 512 + lane * 8);
            ld16(B + (size_t)(c * 16 + l15) * DIMK + k0 + q * 8, sB + c * 512 + lane * 8);
        }
        __syncthreads();                         // tile resident
        short* sOwn = OWN_B ? sB : sA;
        short* sAll = OWN_B ? sA : sB;
        bf16x8 o0 = *(bf16x8*)&sOwn[(w * 2 + 0) * 512 + lane * 8];
        bf16x8 o1 = *(bf16x8*)&sOwn[(w * 2 + 1) * 512 + lane * 8];
#pragma unroll
        for (int nt = 0; nt < 8; nt++) {
            bf16x8 f = *(bf16x8*)&sAll[nt * 512 + lane * 8];
            acc[0][nt] = MFMA(o0, f, acc[0][nt]);
            acc[1][nt] = MFMA(o1, f, acc[1][nt]);
        }
    }
}

// ---------------------------------------------------------------- fused QKV projection
// grid (4, 128, 3): x = inner tile, y = n tile, z = mode (0=q prescaled, 1=k, 2=v)
__global__ __launch_bounds__(256) void proj_qkv(const short* __restrict__ xb,
                                                const short* __restrict__ mb,
                                                const short* __restrict__ wT,
                                                short* __restrict__ qkv) {
    __shared__ __attribute__((aligned(16))) short lds[8192];
    int t = threadIdx.x, lane = t & 63, q = lane >> 4, l15 = lane & 15;
    int w = __builtin_amdgcn_readfirstlane(t >> 6);
    int mode = blockIdx.z;
    const short* A = ((mode == 0) ? xb : mb) + (size_t)blockIdx.y * 128 * DIMK;
    const short* B = wT + (size_t)mode * DIMK * DIMK + (size_t)blockIdx.x * 128 * DIMK;
    fx4 acc[2][8] = {};
    short* dst = qkv + (size_t)mode * MROWS * DIMK;

    if (mode < 2) {
        // D[inner][n]: lane holds 4 consecutive inner (d) -> b64 stores into [bh][n][d]
        gemm97<1>(A, B, lds, acc, w, lane, q, l15);
        float sc = (mode == 0) ? (float)SCALE_LOG2E : 1.0f;   // fold softmax scale into q
#pragma unroll
        for (int mi = 0; mi < 2; mi++) {
            int inner0 = blockIdx.x * 128 + w * 32 + mi * 16 + q * 4;
            int h = inner0 >> 6, d0 = inner0 & 63;
#pragma unroll
            for (int nj = 0; nj < 8; nj++) {
                int gn = blockIdx.y * 128 + nj * 16 + l15;
                int b = gn >> 11, n = gn & 2047;
                uint2 pv;
                pv.x = pk2bf(acc[mi][nj][0] * sc, acc[mi][nj][1] * sc);
                pv.y = pk2bf(acc[mi][nj][2] * sc, acc[mi][nj][3] * sc);
                *(uint2*)&dst[(((size_t)(b * 8 + h) * SEQ + n) << 6) + d0] = pv;
            }
        }
    } else {
        // D[n][inner]: lane holds 4 consecutive n (j) -> b64 stores into vT[bh*64+d][j]
        gemm97<0>(A, B, lds, acc, w, lane, q, l15);
#pragma unroll
        for (int mt = 0; mt < 2; mt++) {
            int gm0 = blockIdx.y * 128 + w * 32 + mt * 16 + q * 4;  // global act row base
            int b = gm0 >> 11, j0 = gm0 & 2047;
#pragma unroll
            for (int nt = 0; nt < 8; nt++) {
                int inner = blockIdx.x * 128 + nt * 16 + l15;       // h*64+d
                uint2 pv;
                pv.x = pk2bf(acc[mt][nt][0], acc[mt][nt][1]);
                pv.y = pk2bf(acc[mt][nt][2], acc[mt][nt][3]);
                *(uint2*)&dst[((size_t)b * 512 + inner) * SEQ + j0] = pv;
            }
        }
    }
}

// ---------------------------------------------------------------- output projection (transposed)
// grid (4, 128): x = out-col tile, y = m tile. Lane holds 4 consecutive out-cols -> float4 stores.
__global__ __launch_bounds__(256) void out_proj(const short* __restrict__ ob,
                                                const short* __restrict__ woT,
                                                const float* __restrict__ bo,
                                                float* __restrict__ out) {
    __shared__ __attribute__((aligned(16))) short lds[8192];
    int t = threadIdx.x, lane = t & 63, q = lane >> 4, l15 = lane & 15;
    int w = __builtin_amdgcn_readfirstlane(t >> 6);
    const short* A = ob + (size_t)blockIdx.y * 128 * DIMK;
    const short* B = woT + (size_t)blockIdx.x * 128 * DIMK;
    fx4 acc[2][8] = {};
    gemm97<1>(A, B, lds, acc, w, lane, q, l15);

#pragma unroll
    for (int mi = 0; mi < 2; mi++) {
        int gn0 = blockIdx.x * 128 + w * 32 + mi * 16 + q * 4;  // out col base
        float4 b4 = *(const float4*)&bo[gn0];
#pragma unroll
        for (int nj = 0; nj < 8; nj++) {
            int n = blockIdx.y * 128 + nj * 16 + l15;           // act row
            float4 v;
            v.x = acc[mi][nj][0] + b4.x;
            v.y = acc[mi][nj][1] + b4.y;
            v.z = acc[mi][nj][2] + b4.z;
            v.w = acc[mi][nj][3] + b4.w;
            *(float4*)&out[(size_t)n * DIMK + gn0] = v;
        }
    }
}

// ---------------------------------------------------------------- flash attention (S^T form)
// grid (64, 16): bh = blockIdx.x (XCD swizzle: all i-tiles of a bh have id ≡ bh mod 8 ->
// same XCD -> per-XCD K/V working set = 8 bh x 512 KB = 4 MB = L2). Wave w owns 32 q rows.
// Q pre-scaled by SCALE*log2e. Row-sums via ones-MFMA. Static softmax (inputs bounded).
__global__ __launch_bounds__(256, 4) void attn_kernel(const short* __restrict__ qg,
                                                      const short* __restrict__ kg,
                                                      const short* __restrict__ vg,
                                                      short* __restrict__ o) {
    // [buf0: K 4096 | V 4096][buf1: K | V][sP 4096 shorts = 1024/wave]
    __shared__ __attribute__((aligned(16))) short lds[2 * 8192 + 4096];
    int t = threadIdx.x, lane = t & 63, q = lane >> 4, l15 = lane & 15;
    int w = __builtin_amdgcn_readfirstlane(t >> 6);
    int bh = blockIdx.x;
    int i0 = blockIdx.y * 128;
    const short* qbh = qg + (size_t)bh * SEQ * DHEAD;
    short* sP = lds + 16384 + w * 1024;   // wave-local 2KB

    const bf16x8 ones = {0x3F80, 0x3F80, 0x3F80, 0x3F80, 0x3F80, 0x3F80, 0x3F80, 0x3F80};

    // incremental staging pointers (k: row j0+w*16+l15; v: row d=w*16+l15, col j0)
    const short* kp = kg + (size_t)bh * SEQ * DHEAD + (w * 16 + l15) * DHEAD + q * 8;
    const short* vp = vg + (size_t)bh * DHEAD * SEQ + (w * 16 + l15) * SEQ + q * 8;

    auto issueKV = [&](int j0, short* bb) {
        const short* kj = kp + (size_t)j0 * DHEAD;
        const short* vj = vp + j0;
        short* d = bb + w * 2 * 512 + lane * 8;
        ld16(kj,      d);
        ld16(kj + 32, d + 512);
        ld16(vj,      d + 4096);
        ld16(vj + 32, d + 4096 + 512);
    };

    // prologue: stage Q (128x64 = 16KB) through buf0, then reclaim buf0 for K/V
#pragma unroll
    for (int j = 0; j < 4; j++) {
        int c = w * 4 + j;                // chunk c = w*4 + it*2 + ks
        ld16(qbh + (size_t)(i0 + (c >> 1) * 16 + l15) * DHEAD + (c & 1) * 32 + q * 8,
             lds + c * 512 + lane * 8);
    }
    __syncthreads();                      // Q resident
    bf16x8 aq[2][2];
#pragma unroll
    for (int it = 0; it < 2; it++)
#pragma unroll
        for (int ks = 0; ks < 2; ks++)
            aq[it][ks] = *(bf16x8*)&lds[(w * 4 + it * 2 + ks) * 512 + lane * 8];
    __syncthreads();                      // all waves' Q fragment reads done
    issueKV(0, lds);                      // tile 0 -> buf0 (overwrites Q)
    issueKV(64, lds + 8192);              // tile 1 -> buf1
    __syncthreads();                      // tiles 0,1 resident

    fx4 oacc[2][4] = {};
    fx4 sacc[2] = {};                     // P row-sums via ones-MFMA

    auto compute = [&](short* bb) {
        short* sKb = bb;
        short* sVb = bb + 4096;
        // S^T = K @ Q^T : lane holds S[i = it*16+l15][j = jt*16 + q*4 + r], pre-scaled
        fx4 s[2][4];
#pragma unroll
        for (int jt = 0; jt < 4; jt++) {
            bf16x8 ak0 = *(bf16x8*)&sKb[(jt * 2 + 0) * 512 + lane * 8];
            bf16x8 ak1 = *(bf16x8*)&sKb[(jt * 2 + 1) * 512 + lane * 8];
#pragma unroll
            for (int it = 0; it < 2; it++) {
                fx4 z = {0.f, 0.f, 0.f, 0.f};
                z = MFMA(ak0, aq[it][0], z);
                z = MFMA(ak1, aq[it][1], z);
                s[it][jt] = z;
            }
        }
        // static softmax numerator; per it: batch all 4 b64 writes, then 2 b128 reads
        bf16x8 bp[2][2];
#pragma unroll
        for (int it = 0; it < 2; it++) {
#pragma unroll
            for (int jt = 0; jt < 4; jt++) {
                float p0 = __builtin_amdgcn_exp2f(s[it][jt][0]);
                float p1 = __builtin_amdgcn_exp2f(s[it][jt][1]);
                float p2 = __builtin_amdgcn_exp2f(s[it][jt][2]);
                float p3 = __builtin_amdgcn_exp2f(s[it][jt][3]);
                uint2 pv; pv.x = pk2bf(p0, p1); pv.y = pk2bf(p2, p3);
                // element (i=l15, j=jt*16+q*4+r) -> chunk ks=jt>>1, q'=(jt&1)*2+(q>>1)
                *(uint2*)&sP[(jt >> 1) * 512 +
                             (((jt & 1) * 2 + (q >> 1)) * 16 + l15) * 8 + (q & 1) * 4] = pv;
            }
            // wave-local DS ops are in-order: reads see the 4 writes above
            bp[it][0] = *(bf16x8*)&sP[lane * 8];
            bp[it][1] = *(bf16x8*)&sP[512 + lane * 8];
            sacc[it] = MFMA(ones, bp[it][0], sacc[it]);
            sacc[it] = MFMA(ones, bp[it][1], sacc[it]);
        }
        // O^T += V^T @ P^T
#pragma unroll
        for (int dt = 0; dt < 4; dt++) {
            bf16x8 av0 = *(bf16x8*)&sVb[(dt * 2 + 0) * 512 + lane * 8];
            bf16x8 av1 = *(bf16x8*)&sVb[(dt * 2 + 1) * 512 + lane * 8];
#pragma unroll
            for (int it = 0; it < 2; it++) {
                oacc[it][dt] = MFMA(av0, bp[it][0], oacc[it][dt]);
                oacc[it][dt] = MFMA(av1, bp[it][1], oacc[it][dt]);
            }
        }
    };

    compute(lds);                         // tile 0
    for (int ti = 1; ti < 32; ti++) {
        __syncthreads();                  // tile ti resident; buf[(ti+1)&1] reads done
        if (ti < 31) issueKV((ti + 1) * 64, lds + ((ti + 1) & 1) * 8192);
        compute(lds + (ti & 1) * 8192);
    }

    // epilogue: lane holds its row-sum in sacc[it][0] (all r equal, i = it*16+l15)
    int b = bh >> 3, h = bh & 7;
#pragma unroll
    for (int it = 0; it < 2; it++) {
        float rl = 1.0f / sacc[it][0];
        int i = i0 + w * 32 + it * 16 + l15;
        size_t base = ((size_t)(b * SEQ + i) * DIMK) + h * DHEAD;
#pragma unroll
        for (int dt = 0; dt < 4; dt++) {
            uint2 pv;
            pv.x = pk2bf(oacc[it][dt][0] * rl, oacc[it][dt][1] * rl);
            pv.y = pk2bf(oacc[it][dt][2] * rl, oacc[it][dt][3] * rl);
            *(uint2*)&o[base + dt * 16 + q * 4] = pv;
        }
    }
}

// ---------------------------------------------------------------- launch
extern "C" void kernel_launch(void* const* d_in, const int* in_sizes, int n_in,
                              void* d_out, int out_size, void* d_ws, size_t ws_size,
                              hipStream_t stream) {
    const float* x  = (const float*)d_in[0];
    const float* m  = (const float*)d_in[1];
    const float* Wq = (const float*)d_in[2];
    const float* Wk = (const float*)d_in[3];
    const float* Wv = (const float*)d_in[4];
    const float* Wo = (const float*)d_in[5];
    const float* bo = (const float*)d_in[6];
    float* out = (float*)d_out;

    char* ws = (char*)d_ws;
    const size_t XB_BYTES = (size_t)MROWS * DIMK * 2;      // 16 MiB
    const size_t WT_ONE   = (size_t)DIMK * DIMK;           // elements per weight
    short* xb  = (short*)(ws);
    short* mb  = (short*)(ws + XB_BYTES);
    short* wT  = (short*)(ws + 2 * XB_BYTES);              // 4 x 512x512 bf16 = 2 MiB
    short* qkv = (short*)(ws + 2 * XB_BYTES + 4 * WT_ONE * 2);
    short* ob  = xb;   // xb dead after proj_qkv; reuse as attention output

    cvt_kernel<<<16384, 256, 0, stream>>>(x, m, xb, mb);
    wtrans_kernel<<<dim3(16, 16, 4), dim3(32, 8), 0, stream>>>(Wq, Wk, Wv, Wo, wT);
    proj_qkv<<<dim3(4, 128, 3), 256, 0, stream>>>(xb, mb, wT, qkv);
    attn_kernel<<<dim3(BATCH * HEADS, SEQ / 128), 256, 0, stream>>>(
        qkv, qkv + (size_t)MROWS * DIMK, qkv + 2 * (size_t)MROWS * DIMK, ob);
    out_proj<<<dim3(4, 128), 256, 0, stream>>>(ob, wT + 3 * WT_ONE, bo, out);
}